// Round 1
// baseline (1985.679 us; speedup 1.0000x reference)
//
#include <hip/hip_runtime.h>
#include <stdint.h>

typedef short short8 __attribute__((ext_vector_type(8)));
typedef float floatx4 __attribute__((ext_vector_type(4)));

#define NPTS 16384
#define TILE_M 64
#define THREADS 512

__device__ inline unsigned short f2bf(float f) {
  union { float f; unsigned u; } v; v.f = f;
  unsigned u = v.u;
  unsigned r = (u + 0x7fffu + ((u >> 16) & 1u)) >> 16;
  return (unsigned short)r;
}
__device__ inline float bf2f(unsigned short h) {
  union { unsigned u; float f; } v; v.u = ((unsigned)h) << 16;
  return v.f;
}

// async global->LDS, 16B per lane; LDS dest must be wave-uniform base + lane*16
__device__ inline void gload_lds16(const unsigned short* g, unsigned short* l) {
  auto gp = (const __attribute__((address_space(1))) unsigned int*)(uintptr_t)(const void*)g;
  auto lp = (__attribute__((address_space(3))) unsigned int*)(uintptr_t)(void*)l;
  __builtin_amdgcn_global_load_lds(gp, lp, 16, 0, 0);
}

// Fused dyn(p_eval) evaluation for 64 points per workgroup.
// p_eval = p + cf*kprev computed inline. Writes k_out (mode 0) or the RK4
// update p + dt/6*(k1+2k2+2k3+k4) (mode 1).
__global__ __launch_bounds__(THREADS, 2) void dyn_kernel(
    const float* __restrict__ p, const float* __restrict__ kprev, float cf,
    const unsigned short* __restrict__ w2, const unsigned short* __restrict__ w3,
    const float* __restrict__ sf, const float* __restrict__ w1,
    const float* __restrict__ b1, const float* __restrict__ b2,
    const float* __restrict__ b3, const float* __restrict__ w4,
    const float* __restrict__ b4, int update_mode, float* __restrict__ outp,
    const float* __restrict__ k1v, const float* __restrict__ k2v,
    const float* __restrict__ k3v, float dt6)
{
  // act: 64 x 512 bf16 activations, row pitch 520 (=1040B, 16B aligned, breaks
  // the 1024B power-of-2 bank stride for A-fragment ds_read_b128)
  __shared__ unsigned short act[TILE_M][520];
  // weight staging: [buf][k8*512 + n][8] -- contiguous 16B MFMA B-fragments,
  // layout compatible with global_load_lds lane*16 scatter
  __shared__ unsigned short wbuf[2][2048][8];
  __shared__ float pe[TILE_M][3];
  __shared__ float red[192][8];

  const int tid = threadIdx.x;
  const int wg = blockIdx.x;
  const int m0 = wg * TILE_M;
  const int batch = wg >> 6;          // 64 WGs per batch (4096 pts / 64)
  const int lane = tid & 63;
  const int wid = tid >> 6;           // 0..7

  // ---- p_eval for our 64 points ----
  if (tid < TILE_M * 3) {
    int gi = m0 * 3 + tid;
    ((float*)pe)[tid] = p[gi] + cf * kprev[gi];
  }
  __syncthreads();

  // ---- phase 1: h = relu(p@W1.T + b1) * sf  (fp32 math, bf16 store) ----
  {
    int j = tid;                      // one feature column per thread
    float ww0 = w1[j * 3 + 0], ww1 = w1[j * 3 + 1], ww2 = w1[j * 3 + 2];
    float bb = b1[j];
    float s = sf[batch * 512 + j];
    #pragma unroll 4
    for (int m = 0; m < TILE_M; ++m) {
      float v = fmaf(pe[m][0], ww0, fmaf(pe[m][1], ww1, fmaf(pe[m][2], ww2, bb)));
      v = fmaxf(v, 0.f) * s;
      act[m][j] = f2bf(v);
    }
  }
  __syncthreads();

  // ---- phases 2+3: two residual GEMMs h = relu(h@W.T + b) + h ----
  const int mtile = wid & 3;          // 4 M-tiles of 16 rows
  const int nhalf = wid >> 2;         // 2 N-halves of 256 cols
  const int aOffB = (mtile * 16 + (lane & 15)) * 1040 + ((lane >> 4) * 16);
  const int bOffIdx = (lane >> 4) * 512 + nhalf * 256 + (lane & 15);
  const char* actB = (const char*)&act[0][0];

  for (int s = 0; s < 2; ++s) {
    const unsigned short* w = s ? w3 : w2;
    const float* bias = s ? b3 : b2;
    floatx4 acc[16];
    #pragma unroll
    for (int i = 0; i < 16; ++i) acc[i] = (floatx4){0.f, 0.f, 0.f, 0.f};

    // preload kb=0 into buf 0 (4 x 1KB passes per wave; 8 waves cover 32KB)
    #pragma unroll
    for (int pp = 0; pp < 4; ++pp) {
      int flat = (wid * 4 + pp) * 64 + lane;
      int n = flat & 511, k8 = flat >> 9;
      gload_lds16(w + n * 512 + k8 * 8, &wbuf[0][(wid * 4 + pp) * 64][0]);
    }
    for (int kb = 0; kb < 16; ++kb) {
      __syncthreads();                // drains vmcnt -> buf[kb&1] valid
      if (kb < 15) {                  // prefetch next K-tile into other buffer
        int nbuf = (kb + 1) & 1;
        #pragma unroll
        for (int pp = 0; pp < 4; ++pp) {
          int flat = (wid * 4 + pp) * 64 + lane;
          int n = flat & 511, k8 = flat >> 9;
          gload_lds16(w + n * 512 + (kb + 1) * 32 + k8 * 8,
                      &wbuf[nbuf][(wid * 4 + pp) * 64][0]);
        }
      }
      int buf = kb & 1;
      short8 afrag = *(const short8*)(actB + aOffB + kb * 64);
      const short8* bbase = (const short8*)&wbuf[buf][bOffIdx][0];
      #pragma unroll
      for (int nt = 0; nt < 16; ++nt) {
        short8 bfrag = bbase[nt * 16];
        acc[nt] = __builtin_amdgcn_mfma_f32_16x16x32_bf16(afrag, bfrag, acc[nt], 0, 0, 0);
      }
    }
    __syncthreads();
    // epilogue: relu(acc + b) + residual, write back bf16 (each (m,n) owned
    // by exactly one lane/reg -> no cross-wave hazard after the barrier)
    #pragma unroll
    for (int nt = 0; nt < 16; ++nt) {
      int ncol = nhalf * 256 + nt * 16 + (lane & 15);
      float bs = bias[ncol];
      #pragma unroll
      for (int r = 0; r < 4; ++r) {
        int mrow = mtile * 16 + (lane >> 4) * 4 + r;
        float v = fmaxf(acc[nt][r] + bs, 0.f) + bf2f(act[mrow][ncol]);
        act[mrow][ncol] = f2bf(v);
      }
    }
    __syncthreads();
  }

  // ---- phase 4: flow = tanh(h@W4.T + b4), fp32 W4 ----
  {
    int m = tid >> 3, jj = tid & 7;   // 8 threads per point, 64-k slices
    const unsigned short* arow = &act[m][0];
    int k0 = jj * 64;
    float s0 = 0.f, s1 = 0.f, s2 = 0.f;
    #pragma unroll 8
    for (int kk = 0; kk < 64; ++kk) {
      float a = bf2f(arow[k0 + kk]);
      s0 = fmaf(a, w4[k0 + kk], s0);
      s1 = fmaf(a, w4[512 + k0 + kk], s1);
      s2 = fmaf(a, w4[1024 + k0 + kk], s2);
    }
    red[m * 3 + 0][jj] = s0;
    red[m * 3 + 1][jj] = s1;
    red[m * 3 + 2][jj] = s2;
  }
  __syncthreads();
  if (tid < 192) {
    int mm = tid / 3, cc = tid % 3;
    float ssum = 0.f;
    #pragma unroll
    for (int q = 0; q < 8; ++q) ssum += red[tid][q];
    float flow = tanhf(ssum + b4[cc]);
    int gi = (m0 + mm) * 3 + cc;
    if (update_mode) {
      outp[gi] = p[gi] + dt6 * (k1v[gi] + 2.f * k2v[gi] + 2.f * k3v[gi] + flow);
    } else {
      outp[gi] = flow;
    }
  }
}

// ---- setup kernels ----
__global__ void setup_convert(const float* s0, const float* s1, const float* s2,
                              const float* s3, unsigned short* dst) {
  int i = blockIdx.x * blockDim.x + threadIdx.x;   // 4 * 262144 total
  int a = i >> 18, off = i & 262143;
  const float* s = (a == 0) ? s0 : (a == 1) ? s1 : (a == 2) ? s2 : s3;
  dst[i] = f2bf(s[off]);
}

__global__ void setup_copy(const float* x, float* p) {
  int i = blockIdx.x * blockDim.x + threadIdx.x;
  if (i < NPTS * 3) p[i] = x[i];
}

__global__ void setup_sf(const float* code, const float* cw1, const float* cb1,
                         const float* cw2, const float* cb2, float* sfout) {
  int f = blockIdx.x >> 2, b = blockIdx.x & 3;
  const float* cw = f ? cw2 : cw1;
  const float* cb = f ? cb2 : cb1;
  int j = threadIdx.x;
  const float* c = code + b * 512;
  float s = cb[j];
  for (int k = 0; k < 512; ++k) s = fmaf(c[k], cw[j * 512 + k], s);
  sfout[f * 2048 + b * 512 + j] = tanhf(s);
}

extern "C" void kernel_launch(void* const* d_in, const int* in_sizes, int n_in,
                              void* d_out, int out_size, void* d_ws, size_t ws_size,
                              hipStream_t stream) {
  const float* code = (const float*)d_in[0];
  const float* x    = (const float*)d_in[1];
  char* ws = (char*)d_ws;
  // ws layout: p, k1, k2, k3 (fp32 16384x3 each), sf (2x4x512 fp32),
  // bf16 weights [f1w2][f1w3][f2w2][f2w3] -> total ~2.9 MB
  float* p  = (float*)(ws);
  float* k1 = (float*)(ws + 196608);
  float* k2 = (float*)(ws + 2 * 196608);
  float* k3 = (float*)(ws + 3 * 196608);
  float* sf = (float*)(ws + 4 * 196608);
  unsigned short* wbf = (unsigned short*)(ws + 4 * 196608 + 16384);

  setup_convert<<<4096, 256, 0, stream>>>((const float*)d_in[4], (const float*)d_in[6],
                                          (const float*)d_in[14], (const float*)d_in[16], wbf);
  setup_copy<<<192, 256, 0, stream>>>(x, p);
  setup_sf<<<8, 512, 0, stream>>>(code, (const float*)d_in[10], (const float*)d_in[11],
                                  (const float*)d_in[20], (const float*)d_in[21], sf);

  const float dt = 0.05f, dt6 = dt / 6.0f;
  float* out = (float*)d_out;
  for (int f = 0; f < 2; ++f) {
    const float* w1 = (const float*)d_in[2 + f * 10];
    const float* b1 = (const float*)d_in[3 + f * 10];
    const float* b2 = (const float*)d_in[5 + f * 10];
    const float* b3 = (const float*)d_in[7 + f * 10];
    const float* w4 = (const float*)d_in[8 + f * 10];
    const float* b4 = (const float*)d_in[9 + f * 10];
    const unsigned short* w2b = wbf + (f * 2 + 0) * 262144;
    const unsigned short* w3b = wbf + (f * 2 + 1) * 262144;
    const float* sff = sf + f * 2048;
    for (int st = 0; st < 4; ++st) {
      int last = (f == 1 && st == 3);
      dyn_kernel<<<256, THREADS, 0, stream>>>(p, p,  0.0f,      w2b, w3b, sff, w1, b1, b2, b3, w4, b4,
                                              0, k1, p, p, p, dt6);
      dyn_kernel<<<256, THREADS, 0, stream>>>(p, k1, 0.5f * dt, w2b, w3b, sff, w1, b1, b2, b3, w4, b4,
                                              0, k2, p, p, p, dt6);
      dyn_kernel<<<256, THREADS, 0, stream>>>(p, k2, 0.5f * dt, w2b, w3b, sff, w1, b1, b2, b3, w4, b4,
                                              0, k3, p, p, p, dt6);
      dyn_kernel<<<256, THREADS, 0, stream>>>(p, k3, dt,        w2b, w3b, sff, w1, b1, b2, b3, w4, b4,
                                              1, last ? out : p, k1, k2, k3, dt6);
    }
  }
}

// Round 2
// 997.143 us; speedup vs baseline: 1.9914x; 1.9914x over previous
//
#include <hip/hip_runtime.h>
#include <stdint.h>

typedef short short8 __attribute__((ext_vector_type(8)));
typedef float floatx16 __attribute__((ext_vector_type(16)));

#define NPTS 16384
#define TILE_M 64
#define THREADS 512

__device__ inline unsigned short f2bf(float f) {
  union { float f; unsigned u; } v; v.f = f;
  unsigned u = v.u;
  unsigned r = (u + 0x7fffu + ((u >> 16) & 1u)) >> 16;
  return (unsigned short)r;
}
__device__ inline float bf2f(unsigned short h) {
  union { unsigned u; float f; } v; v.u = ((unsigned)h) << 16;
  return v.f;
}

// Fused dyn(p_eval) for 64 points per WG. GEMMs use 32x32x16 bf16 MFMA with
// B-fragments loaded register-direct from a pre-shuffled fragment-major
// weight buffer (zero K-loop barriers; W read exactly once per WG per GEMM).
__global__ __launch_bounds__(THREADS, 2) void dyn_kernel(
    const float* __restrict__ p, const float* __restrict__ kprev, float cf,
    const unsigned short* __restrict__ w2f, const unsigned short* __restrict__ w3f,
    const float* __restrict__ sf, const float* __restrict__ w1,
    const float* __restrict__ b1, const float* __restrict__ b2,
    const float* __restrict__ b3, const float* __restrict__ w4,
    const float* __restrict__ b4, int update_mode, float* __restrict__ outp,
    const float* __restrict__ k1v, const float* __restrict__ k2v,
    const float* __restrict__ k3v, float dt6)
{
  // act: 64 x 512 bf16, row pitch 520 u16 (1040 B = 65*16B -> afrag b128
  // reads land row r on bank-quad r%8 => conflict-free)
  __shared__ unsigned short act[TILE_M][520];
  __shared__ float pe[TILE_M][3];
  __shared__ float red[192][8];

  const int tid = threadIdx.x;
  const int wg = blockIdx.x;
  const int m0 = wg * TILE_M;
  const int batch = wg >> 6;          // 64 WGs per batch
  const int lane = tid & 63;
  const int wid = tid >> 6;           // 0..7: owns cols [wid*64, wid*64+64)

  // ---- p_eval ----
  if (tid < TILE_M * 3) {
    int gi = m0 * 3 + tid;
    ((float*)pe)[tid] = p[gi] + cf * kprev[gi];
  }
  __syncthreads();

  // ---- phase 1: h = relu(p@W1.T + b1) * sf ----
  {
    int j = tid;
    float ww0 = w1[j * 3 + 0], ww1 = w1[j * 3 + 1], ww2 = w1[j * 3 + 2];
    float bb = b1[j];
    float s = sf[batch * 512 + j];
    #pragma unroll 4
    for (int m = 0; m < TILE_M; ++m) {
      float v = fmaf(pe[m][0], ww0, fmaf(pe[m][1], ww1, fmaf(pe[m][2], ww2, bb)));
      v = fmaxf(v, 0.f) * s;
      act[m][j] = f2bf(v);
    }
  }
  __syncthreads();

  // ---- phases 2+3: two residual GEMMs, h = relu(h@W.T + b) + h ----
  // A-frag (32x32x16): lane holds act[mt*32 + (lane&31)][kt*16 + (lane>>5)*8 ..+8]
  // B-frag: fragment-major wf[((kt*16 + nt)*64 + lane)*8]
  const int aBase = (lane & 31) * 1040 + (lane >> 5) * 16;   // bytes
  const char* actB = (const char*)&act[0][0];
  const int bcol0 = (wid * 2 + 0) * 64 + lane;               // short8 index
  const int bcol1 = (wid * 2 + 1) * 64 + lane;

  for (int s = 0; s < 2; ++s) {
    const short8* bptr = (const short8*)(s ? w3f : w2f);
    const float* bias = s ? b3 : b2;
    floatx16 acc00{}, acc01{}, acc10{}, acc11{};

    short8 a0 = *(const short8*)(actB + aBase);
    short8 a1 = *(const short8*)(actB + aBase + 33280);
    short8 bb0 = bptr[bcol0];
    short8 bb1 = bptr[bcol1];

    #pragma unroll 4
    for (int kt = 0; kt < 32; ++kt) {
      int ktn = (kt + 1 < 32) ? kt + 1 : 31;   // clamp: last iter reloads
      short8 an0 = *(const short8*)(actB + aBase + ktn * 32);
      short8 an1 = *(const short8*)(actB + aBase + 33280 + ktn * 32);
      short8 bn0 = bptr[ktn * 1024 + bcol0];
      short8 bn1 = bptr[ktn * 1024 + bcol1];
      acc00 = __builtin_amdgcn_mfma_f32_32x32x16_bf16(a0, bb0, acc00, 0, 0, 0);
      acc01 = __builtin_amdgcn_mfma_f32_32x32x16_bf16(a0, bb1, acc01, 0, 0, 0);
      acc10 = __builtin_amdgcn_mfma_f32_32x32x16_bf16(a1, bb0, acc10, 0, 0, 0);
      acc11 = __builtin_amdgcn_mfma_f32_32x32x16_bf16(a1, bb1, acc11, 0, 0, 0);
      a0 = an0; a1 = an1; bb0 = bn0; bb1 = bn1;
    }

    __syncthreads();   // all waves done reading act before epilogue writes
    // epilogue: C/D layout col=lane&31, row=(reg&3)+8*(reg>>2)+4*(lane>>5)
    {
      int ncol0 = (wid * 2 + 0) * 32 + (lane & 31);
      int ncol1 = (wid * 2 + 1) * 32 + (lane & 31);
      float bs0 = bias[ncol0], bs1 = bias[ncol1];
      int rbase = 4 * (lane >> 5);
      #pragma unroll
      for (int reg = 0; reg < 16; ++reg) {
        int row = (reg & 3) + 8 * (reg >> 2) + rbase;
        {
          float v = fmaxf(acc00[reg] + bs0, 0.f) + bf2f(act[row][ncol0]);
          act[row][ncol0] = f2bf(v);
          v = fmaxf(acc01[reg] + bs1, 0.f) + bf2f(act[row][ncol1]);
          act[row][ncol1] = f2bf(v);
          v = fmaxf(acc10[reg] + bs0, 0.f) + bf2f(act[32 + row][ncol0]);
          act[32 + row][ncol0] = f2bf(v);
          v = fmaxf(acc11[reg] + bs1, 0.f) + bf2f(act[32 + row][ncol1]);
          act[32 + row][ncol1] = f2bf(v);
        }
      }
    }
    __syncthreads();
  }

  // ---- phase 4: flow = tanh(h@W4.T + b4) ----
  // interleaved k = kk*8+jj: lanes (m,jj) -> bank 4m+(jj>>1)+4kk, conflict-free
  {
    int m = tid >> 3, jj = tid & 7;
    const unsigned short* arow = &act[m][0];
    float s0 = 0.f, s1 = 0.f, s2 = 0.f;
    #pragma unroll 8
    for (int kk = 0; kk < 64; ++kk) {
      int k = kk * 8 + jj;
      float a = bf2f(arow[k]);
      s0 = fmaf(a, w4[k], s0);
      s1 = fmaf(a, w4[512 + k], s1);
      s2 = fmaf(a, w4[1024 + k], s2);
    }
    red[m * 3 + 0][jj] = s0;
    red[m * 3 + 1][jj] = s1;
    red[m * 3 + 2][jj] = s2;
  }
  __syncthreads();
  if (tid < 192) {
    int mm = tid / 3, cc = tid % 3;
    float ssum = 0.f;
    #pragma unroll
    for (int q = 0; q < 8; ++q) ssum += red[tid][q];
    float flow = tanhf(ssum + b4[cc]);
    int gi = (m0 + mm) * 3 + cc;
    if (update_mode) {
      outp[gi] = p[gi] + dt6 * (k1v[gi] + 2.f * k2v[gi] + 2.f * k3v[gi] + flow);
    } else {
      outp[gi] = flow;
    }
  }
}

// ---- setup: shuffle W (512x512 fp32 row-major, W[n][k]) into fragment-major
// bf16: dst[((kt*16 + nt)*64 + lane)*8 + j] = W[nt*32+(lane&31)][kt*16+(lane>>5)*8+j]
__global__ void setup_shuffle(const float* s0, const float* s1, const float* s2,
                              const float* s3, unsigned short* dst) {
  int idx = blockIdx.x * blockDim.x + threadIdx.x;   // 4 * 32768
  int w = idx >> 15;
  int r = idx & 32767;            // (kt*16+nt)*64 + lane
  int lane = r & 63;
  int tile = r >> 6;
  int nt = tile & 15, kt = tile >> 4;
  const float* W = (w == 0) ? s0 : (w == 1) ? s1 : (w == 2) ? s2 : s3;
  int n = nt * 32 + (lane & 31);
  int k0 = kt * 16 + (lane >> 5) * 8;
  const float* src = W + n * 512 + k0;
  unsigned short* d = dst + ((size_t)w << 18) + (size_t)r * 8;
  #pragma unroll
  for (int j = 0; j < 8; ++j) d[j] = f2bf(src[j]);
}

__global__ void setup_copy(const float* x, float* p) {
  int i = blockIdx.x * blockDim.x + threadIdx.x;
  if (i < NPTS * 3) p[i] = x[i];
}

__global__ void setup_sf(const float* code, const float* cw1, const float* cb1,
                         const float* cw2, const float* cb2, float* sfout) {
  int f = blockIdx.x >> 2, b = blockIdx.x & 3;
  const float* cw = f ? cw2 : cw1;
  const float* cb = f ? cb2 : cb1;
  int j = threadIdx.x;
  const float* c = code + b * 512;
  float s = cb[j];
  for (int k = 0; k < 512; ++k) s = fmaf(c[k], cw[j * 512 + k], s);
  sfout[f * 2048 + b * 512 + j] = tanhf(s);
}

extern "C" void kernel_launch(void* const* d_in, const int* in_sizes, int n_in,
                              void* d_out, int out_size, void* d_ws, size_t ws_size,
                              hipStream_t stream) {
  const float* code = (const float*)d_in[0];
  const float* x    = (const float*)d_in[1];
  char* ws = (char*)d_ws;
  float* p  = (float*)(ws);
  float* k1 = (float*)(ws + 196608);
  float* k2 = (float*)(ws + 2 * 196608);
  float* k3 = (float*)(ws + 3 * 196608);
  float* sf = (float*)(ws + 4 * 196608);
  unsigned short* wbf = (unsigned short*)(ws + 4 * 196608 + 16384);

  setup_shuffle<<<512, 256, 0, stream>>>((const float*)d_in[4], (const float*)d_in[6],
                                         (const float*)d_in[14], (const float*)d_in[16], wbf);
  setup_copy<<<192, 256, 0, stream>>>(x, p);
  setup_sf<<<8, 512, 0, stream>>>(code, (const float*)d_in[10], (const float*)d_in[11],
                                  (const float*)d_in[20], (const float*)d_in[21], sf);

  const float dt = 0.05f, dt6 = dt / 6.0f;
  float* out = (float*)d_out;
  for (int f = 0; f < 2; ++f) {
    const float* w1 = (const float*)d_in[2 + f * 10];
    const float* b1 = (const float*)d_in[3 + f * 10];
    const float* b2 = (const float*)d_in[5 + f * 10];
    const float* b3 = (const float*)d_in[7 + f * 10];
    const float* w4 = (const float*)d_in[8 + f * 10];
    const float* b4 = (const float*)d_in[9 + f * 10];
    const unsigned short* w2b = wbf + (f * 2 + 0) * 262144;
    const unsigned short* w3b = wbf + (f * 2 + 1) * 262144;
    const float* sff = sf + f * 2048;
    for (int st = 0; st < 4; ++st) {
      int last = (f == 1 && st == 3);
      dyn_kernel<<<256, THREADS, 0, stream>>>(p, p,  0.0f,      w2b, w3b, sff, w1, b1, b2, b3, w4, b4,
                                              0, k1, p, p, p, dt6);
      dyn_kernel<<<256, THREADS, 0, stream>>>(p, k1, 0.5f * dt, w2b, w3b, sff, w1, b1, b2, b3, w4, b4,
                                              0, k2, p, p, p, dt6);
      dyn_kernel<<<256, THREADS, 0, stream>>>(p, k2, 0.5f * dt, w2b, w3b, sff, w1, b1, b2, b3, w4, b4,
                                              0, k3, p, p, p, dt6);
      dyn_kernel<<<256, THREADS, 0, stream>>>(p, k3, dt,        w2b, w3b, sff, w1, b1, b2, b3, w4, b4,
                                              1, last ? out : p, k1, k2, k3, dt6);
    }
  }
}

// Round 3
// 945.492 us; speedup vs baseline: 2.1002x; 1.0546x over previous
//
#include <hip/hip_runtime.h>
#include <stdint.h>

typedef short short8 __attribute__((ext_vector_type(8)));
typedef float floatx16 __attribute__((ext_vector_type(16)));

#define NPTS 16384
#define TILE_M 64
#define THREADS 512
#define PA 4   // A-fragment (LDS) prefetch depth
#define PB 8   // B-fragment (global/L2) prefetch depth

__device__ inline unsigned short f2bf(float f) {
  union { float f; unsigned u; } v; v.f = f;
  unsigned u = v.u;
  unsigned r = (u + 0x7fffu + ((u >> 16) & 1u)) >> 16;
  return (unsigned short)r;
}
__device__ inline float bf2f(unsigned short h) {
  union { unsigned u; float f; } v; v.u = ((unsigned)h) << 16;
  return v.f;
}

// Fused dyn(p_eval) for 64 points per WG. GEMMs use 32x32x16 bf16 MFMA with
// B-fragments register-prefetched PB-1 iterations ahead from a fragment-major
// weight buffer (zero K-loop barriers; W read exactly once per WG per GEMM).
__global__ __launch_bounds__(THREADS, 2) void dyn_kernel(
    const float* __restrict__ p, const float* __restrict__ kprev, float cf,
    const unsigned short* __restrict__ w2f, const unsigned short* __restrict__ w3f,
    const float* __restrict__ sf, const float* __restrict__ w1,
    const float* __restrict__ b1, const float* __restrict__ b2,
    const float* __restrict__ b3, const float* __restrict__ w4,
    const float* __restrict__ b4, int update_mode, float* __restrict__ outp,
    const float* __restrict__ k1v, const float* __restrict__ k2v,
    const float* __restrict__ k3v, float dt6)
{
  // act: 64 x 512 bf16, row pitch 520 u16 (1040 B = 65*16B -> afrag b128
  // reads land row r on bank-quad r%8 => conflict-free)
  __shared__ unsigned short act[TILE_M][520];
  __shared__ float pe[TILE_M][3];
  __shared__ float red[192][8];

  const int tid = threadIdx.x;
  const int wg = blockIdx.x;
  const int m0 = wg * TILE_M;
  const int batch = wg >> 6;          // 64 WGs per batch
  const int lane = tid & 63;
  const int wid = tid >> 6;           // 0..7: owns cols [wid*64, wid*64+64)

  // ---- p_eval ----
  if (tid < TILE_M * 3) {
    int gi = m0 * 3 + tid;
    ((float*)pe)[tid] = p[gi] + cf * kprev[gi];
  }
  __syncthreads();

  // ---- phase 1: h = relu(p@W1.T + b1) * sf ----
  {
    int j = tid;
    float ww0 = w1[j * 3 + 0], ww1 = w1[j * 3 + 1], ww2 = w1[j * 3 + 2];
    float bb = b1[j];
    float s = sf[batch * 512 + j];
    #pragma unroll 4
    for (int m = 0; m < TILE_M; ++m) {
      float v = fmaf(pe[m][0], ww0, fmaf(pe[m][1], ww1, fmaf(pe[m][2], ww2, bb)));
      v = fmaxf(v, 0.f) * s;
      act[m][j] = f2bf(v);
    }
  }
  __syncthreads();

  // ---- phases 2+3: two residual GEMMs, h = relu(h@W.T + b) + h ----
  // A-frag (32x32x16): lane holds act[mt*32 + (lane&31)][kt*16 + (lane>>5)*8 ..+8]
  // B-frag: fragment-major wf[((kt*16 + nt)*64 + lane)*8]
  const int aBase = (lane & 31) * 1040 + (lane >> 5) * 16;   // bytes
  const char* actB = (const char*)&act[0][0];
  const int bcol0 = (wid * 2 + 0) * 64 + lane;               // short8 index
  const int bcol1 = (wid * 2 + 1) * 64 + lane;

  for (int s = 0; s < 2; ++s) {
    const short8* bptr = (const short8*)(s ? w3f : w2f);
    const float* bias = s ? b3 : b2;
    const short8* bp0 = bptr + bcol0;
    const short8* bp1 = bptr + bcol1;
    floatx16 acc00{}, acc01{}, acc10{}, acc11{};

    short8 aq0[PA], aq1[PA], bq0[PB], bq1[PB];
    #pragma unroll
    for (int i = 0; i < PB - 1; ++i) {
      bq0[i] = bp0[i * 1024];
      bq1[i] = bp1[i * 1024];
    }
    #pragma unroll
    for (int i = 0; i < PA - 1; ++i) {
      aq0[i] = *(const short8*)(actB + aBase + i * 32);
      aq1[i] = *(const short8*)(actB + aBase + 33280 + i * 32);
    }

    #pragma unroll
    for (int kt = 0; kt < 32; ++kt) {
      int la = kt + PA - 1;
      if (la < 32) {
        aq0[la % PA] = *(const short8*)(actB + aBase + la * 32);
        aq1[la % PA] = *(const short8*)(actB + aBase + 33280 + la * 32);
      }
      int lb = kt + PB - 1;
      if (lb < 32) {
        bq0[lb % PB] = bp0[lb * 1024];
        bq1[lb % PB] = bp1[lb * 1024];
      }
      acc00 = __builtin_amdgcn_mfma_f32_32x32x16_bf16(aq0[kt % PA], bq0[kt % PB], acc00, 0, 0, 0);
      acc01 = __builtin_amdgcn_mfma_f32_32x32x16_bf16(aq0[kt % PA], bq1[kt % PB], acc01, 0, 0, 0);
      acc10 = __builtin_amdgcn_mfma_f32_32x32x16_bf16(aq1[kt % PA], bq0[kt % PB], acc10, 0, 0, 0);
      acc11 = __builtin_amdgcn_mfma_f32_32x32x16_bf16(aq1[kt % PA], bq1[kt % PB], acc11, 0, 0, 0);
    }

    __syncthreads();   // all waves done reading act before epilogue writes
    // epilogue: C/D layout col=lane&31, row=(reg&3)+8*(reg>>2)+4*(lane>>5)
    {
      int ncol0 = (wid * 2 + 0) * 32 + (lane & 31);
      int ncol1 = (wid * 2 + 1) * 32 + (lane & 31);
      float bs0 = bias[ncol0], bs1 = bias[ncol1];
      int rbase = 4 * (lane >> 5);
      #pragma unroll
      for (int reg = 0; reg < 16; ++reg) {
        int row = (reg & 3) + 8 * (reg >> 2) + rbase;
        float v = fmaxf(acc00[reg] + bs0, 0.f) + bf2f(act[row][ncol0]);
        act[row][ncol0] = f2bf(v);
        v = fmaxf(acc01[reg] + bs1, 0.f) + bf2f(act[row][ncol1]);
        act[row][ncol1] = f2bf(v);
        v = fmaxf(acc10[reg] + bs0, 0.f) + bf2f(act[32 + row][ncol0]);
        act[32 + row][ncol0] = f2bf(v);
        v = fmaxf(acc11[reg] + bs1, 0.f) + bf2f(act[32 + row][ncol1]);
        act[32 + row][ncol1] = f2bf(v);
      }
    }
    __syncthreads();
  }

  // ---- phase 4: flow = tanh(h@W4.T + b4) ----
  // interleaved k = kk*8+jj: conflict-free LDS access
  {
    int m = tid >> 3, jj = tid & 7;
    const unsigned short* arow = &act[m][0];
    float s0 = 0.f, s1 = 0.f, s2 = 0.f;
    #pragma unroll 8
    for (int kk = 0; kk < 64; ++kk) {
      int k = kk * 8 + jj;
      float a = bf2f(arow[k]);
      s0 = fmaf(a, w4[k], s0);
      s1 = fmaf(a, w4[512 + k], s1);
      s2 = fmaf(a, w4[1024 + k], s2);
    }
    red[m * 3 + 0][jj] = s0;
    red[m * 3 + 1][jj] = s1;
    red[m * 3 + 2][jj] = s2;
  }
  __syncthreads();
  if (tid < 192) {
    int mm = tid / 3, cc = tid % 3;
    float ssum = 0.f;
    #pragma unroll
    for (int q = 0; q < 8; ++q) ssum += red[tid][q];
    float flow = tanhf(ssum + b4[cc]);
    int gi = (m0 + mm) * 3 + cc;
    if (update_mode) {
      outp[gi] = p[gi] + dt6 * (k1v[gi] + 2.f * k2v[gi] + 2.f * k3v[gi] + flow);
    } else {
      outp[gi] = flow;
    }
  }
}

// ---- setup: shuffle W (512x512 fp32 row-major, W[n][k]) into fragment-major
// bf16: dst[((kt*16 + nt)*64 + lane)*8 + j] = W[nt*32+(lane&31)][kt*16+(lane>>5)*8+j]
__global__ void setup_shuffle(const float* s0, const float* s1, const float* s2,
                              const float* s3, unsigned short* dst) {
  int idx = blockIdx.x * blockDim.x + threadIdx.x;   // 4 * 32768
  int w = idx >> 15;
  int r = idx & 32767;            // (kt*16+nt)*64 + lane
  int lane = r & 63;
  int tile = r >> 6;
  int nt = tile & 15, kt = tile >> 4;
  const float* W = (w == 0) ? s0 : (w == 1) ? s1 : (w == 2) ? s2 : s3;
  int n = nt * 32 + (lane & 31);
  int k0 = kt * 16 + (lane >> 5) * 8;
  const float* src = W + n * 512 + k0;
  unsigned short* d = dst + ((size_t)w << 18) + (size_t)r * 8;
  #pragma unroll
  for (int j = 0; j < 8; ++j) d[j] = f2bf(src[j]);
}

__global__ void setup_copy(const float* x, float* p) {
  int i = blockIdx.x * blockDim.x + threadIdx.x;
  if (i < NPTS * 3) p[i] = x[i];
}

__global__ void setup_sf(const float* code, const float* cw1, const float* cb1,
                         const float* cw2, const float* cb2, float* sfout) {
  int f = blockIdx.x >> 2, b = blockIdx.x & 3;
  const float* cw = f ? cw2 : cw1;
  const float* cb = f ? cb2 : cb1;
  int j = threadIdx.x;
  const float* c = code + b * 512;
  float s = cb[j];
  for (int k = 0; k < 512; ++k) s = fmaf(c[k], cw[j * 512 + k], s);
  sfout[f * 2048 + b * 512 + j] = tanhf(s);
}

extern "C" void kernel_launch(void* const* d_in, const int* in_sizes, int n_in,
                              void* d_out, int out_size, void* d_ws, size_t ws_size,
                              hipStream_t stream) {
  const float* code = (const float*)d_in[0];
  const float* x    = (const float*)d_in[1];
  char* ws = (char*)d_ws;
  float* p  = (float*)(ws);
  float* k1 = (float*)(ws + 196608);
  float* k2 = (float*)(ws + 2 * 196608);
  float* k3 = (float*)(ws + 3 * 196608);
  float* sf = (float*)(ws + 4 * 196608);
  unsigned short* wbf = (unsigned short*)(ws + 4 * 196608 + 16384);

  setup_shuffle<<<512, 256, 0, stream>>>((const float*)d_in[4], (const float*)d_in[6],
                                         (const float*)d_in[14], (const float*)d_in[16], wbf);
  setup_copy<<<192, 256, 0, stream>>>(x, p);
  setup_sf<<<8, 512, 0, stream>>>(code, (const float*)d_in[10], (const float*)d_in[11],
                                  (const float*)d_in[20], (const float*)d_in[21], sf);

  const float dt = 0.05f, dt6 = dt / 6.0f;
  float* out = (float*)d_out;
  for (int f = 0; f < 2; ++f) {
    const float* w1 = (const float*)d_in[2 + f * 10];
    const float* b1 = (const float*)d_in[3 + f * 10];
    const float* b2 = (const float*)d_in[5 + f * 10];
    const float* b3 = (const float*)d_in[7 + f * 10];
    const float* w4 = (const float*)d_in[8 + f * 10];
    const float* b4 = (const float*)d_in[9 + f * 10];
    const unsigned short* w2b = wbf + (f * 2 + 0) * 262144;
    const unsigned short* w3b = wbf + (f * 2 + 1) * 262144;
    const float* sff = sf + f * 2048;
    for (int st = 0; st < 4; ++st) {
      int last = (f == 1 && st == 3);
      dyn_kernel<<<256, THREADS, 0, stream>>>(p, p,  0.0f,      w2b, w3b, sff, w1, b1, b2, b3, w4, b4,
                                              0, k1, p, p, p, dt6);
      dyn_kernel<<<256, THREADS, 0, stream>>>(p, k1, 0.5f * dt, w2b, w3b, sff, w1, b1, b2, b3, w4, b4,
                                              0, k2, p, p, p, dt6);
      dyn_kernel<<<256, THREADS, 0, stream>>>(p, k2, 0.5f * dt, w2b, w3b, sff, w1, b1, b2, b3, w4, b4,
                                              0, k3, p, p, p, dt6);
      dyn_kernel<<<256, THREADS, 0, stream>>>(p, k3, dt,        w2b, w3b, sff, w1, b1, b2, b3, w4, b4,
                                              1, last ? out : p, k1, k2, k3, dt6);
    }
  }
}